// Round 1
// 599.002 us; speedup vs baseline: 1.0144x; 1.0144x over previous
//
#include <hip/hip_runtime.h>

typedef __bf16 bf16_t;
typedef __bf16 bf16x8 __attribute__((ext_vector_type(8)));
typedef __bf16 bf16x4 __attribute__((ext_vector_type(4)));
typedef __bf16 bf16x2 __attribute__((ext_vector_type(2)));
typedef float f32x4 __attribute__((ext_vector_type(4)));

#define DEV __device__ __forceinline__
#define MFMA16 __builtin_amdgcn_mfma_f32_16x16x32_bf16

constexpr int Bb = 2, Ls = 512, Dd = 1024, Hh = 16, HD = 64, Mm = 16384, TK = 8;
constexpr int KSPLIT = 4;          // key splits for topk occupancy
constexpr int CAP = 40;            // candidate buffer per (query, split); E[count]~9
constexpr int NQ = Bb * Ls * Hh;   // 16384 query-heads; bh-major qid = (b*16+h)*512 + l
constexpr int CH = 3;              // attention chunks: mem 24/24/16 tiles + local on chunk 2

// f32-unit workspace layout (~43 MB; >=47.3 MB known available from R4)
constexpr size_t OFF_QF   = 0;                                    // Q f32 [NQ][64]
constexpr size_t OFF_KF   = OFF_QF + (size_t)NQ * HD;             // K f32 [NQ][64]
constexpr size_t OFF_VF   = OFF_KF + (size_t)NQ * HD;             // V f32 [NQ][64]
constexpr size_t OFF_QH   = OFF_VF + (size_t)NQ * HD;             // Q hi bf16 [NQ][64]
constexpr size_t OFF_QL   = OFF_QH + (size_t)NQ * HD / 2;         // Q lo bf16
constexpr size_t OFF_KHG  = OFF_QL + (size_t)NQ * HD / 2;         // mem keys bf16 [M][64]
constexpr size_t OFF_FCAND = OFF_KHG + (size_t)Mm * HD / 2;       // int [KSPLIT][NQ][CAP]
constexpr size_t OFF_FCNT  = OFF_FCAND + (size_t)KSPLIT * NQ * CAP; // int [KSPLIT][NQ]
constexpr size_t OFF_F8   = OFF_FCNT + (size_t)KSPLIT * NQ;       // int [NQ][8]
constexpr size_t OFF_ML   = OFF_F8 + (size_t)NQ * TK;             // (m,l) [CH][NQ][2]
constexpr size_t OFF_PA   = OFF_ML + (size_t)CH * NQ * 2;         // acc [CH][NQ][64]
constexpr size_t WS_ELEMS = OFF_PA + (size_t)CH * NQ * HD + 16;
constexpr size_t WS_BYTES = WS_ELEMS * 4;

DEV void ld8f(const float* p, float* dst) {
  float4 a = *(const float4*)p, b = *(const float4*)(p + 4);
  dst[0]=a.x; dst[1]=a.y; dst[2]=a.z; dst[3]=a.w;
  dst[4]=b.x; dst[5]=b.y; dst[6]=b.z; dst[7]=b.w;
}

DEV void split8(const float* av, bf16x8& hi, bf16x8& lo) {
#pragma unroll
  for (int j = 0; j < 8; ++j) {
    bf16_t h_ = (bf16_t)av[j];
    hi[j] = h_;
    lo[j] = (bf16_t)(av[j] - (float)h_);
  }
}

// 8B-aligned bf16x8 load (rows of stride-68 bf16 arrays are 8B- but not 16B-aligned)
DEV bf16x8 ld8h(const bf16_t* p) {
  bf16x4 a = *(const bf16x4*)p;
  bf16x4 b = *(const bf16x4*)(p + 4);
  bf16x8 r;
#pragma unroll
  for (int i = 0; i < 4; ++i) { r[i] = a[i]; r[i + 4] = b[i]; }
  return r;
}

__global__ __launch_bounds__(256) void ws_sentinel(float* __restrict__ out, int n, float v) {
  int i = blockIdx.x * 256 + threadIdx.x;
  if (i < n) out[i] = v;
}

// ---------------- Kernel 0: pre-convert memory keys to bf16 (once) ----------------
__global__ __launch_bounds__(256) void prep_keys(const float* __restrict__ mk,
                                                 bf16_t* __restrict__ khg) {
  const size_t i = ((size_t)blockIdx.x * 256 + threadIdx.x) * 8;
  float v[8]; ld8f(mk + i, v);
  bf16x8 h;
#pragma unroll
  for (int j = 0; j < 8; ++j) h[j] = (bf16_t)v[j];
  *(bf16x8*)(khg + i) = h;
}

// ---------------- Kernel 1: QKV projection, 3-term split MFMA (~f32-exact) ----------------
__global__ __launch_bounds__(256) void qkv_mfma(
    const float* __restrict__ x,
    const float* __restrict__ Wq, const float* __restrict__ bq,
    const float* __restrict__ Wk, const float* __restrict__ bk,
    const float* __restrict__ Wv, const float* __restrict__ bv,
    float* __restrict__ qf, bf16_t* __restrict__ qh, bf16_t* __restrict__ ql,
    float* __restrict__ kf, float* __restrict__ vf) {
  const int z = blockIdx.z;
  const float* W    = (z == 0) ? Wq : ((z == 1) ? Wk : Wv);
  const float* bias = (z == 0) ? bq : ((z == 1) ? bk : bv);
  const int tid = threadIdx.x;
  const int lane = tid & 63, wv = tid >> 6;
  const int l15 = lane & 15, quad = lane >> 4;
  const int mrow = blockIdx.x * 64 + wv * 16 + l15;
  const int ncol0 = blockIdx.y * 64;
  f32x4 acc[4] = {};
  const size_t abase = (size_t)mrow * Dd + quad * 8;
  for (int kk = 0; kk < Dd; kk += 32) {
    float av[8]; ld8f(x + abase + kk, av);
    bf16x8 ahi, alo; split8(av, ahi, alo);
#pragma unroll
    for (int t = 0; t < 4; ++t) {
      float bv8[8]; ld8f(W + (size_t)(ncol0 + t * 16 + l15) * Dd + kk + quad * 8, bv8);
      bf16x8 bhi, blo; split8(bv8, bhi, blo);
      acc[t] = MFMA16(ahi, bhi, acc[t], 0, 0, 0);
      acc[t] = MFMA16(alo, bhi, acc[t], 0, 0, 0);
      acc[t] = MFMA16(ahi, blo, acc[t], 0, 0, 0);
    }
  }
#pragma unroll
  for (int t = 0; t < 4; ++t) {
    int col = ncol0 + t * 16 + l15;
    int h = col >> 6, hd = col & 63;
    float bb = bias[col];
#pragma unroll
    for (int r = 0; r < 4; ++r) {
      int row = blockIdx.x * 64 + wv * 16 + quad * 4 + r;   // token row = b*512+l
      int b = row >> 9, l = row & 511;
      float val = acc[t][r] + bb;
      size_t o = ((size_t)(b * Hh + h) * Ls + l) * HD + hd;
      if (z == 0) {
        qf[o] = val;
        bf16_t hv = (bf16_t)val;
        qh[o] = hv;
        ql[o] = (bf16_t)(val - (float)hv);
      } else if (z == 1) {
        kf[o] = val;
      } else {
        vf[o] = val;
      }
    }
  }
}

// ---------------- Kernel 2: threshold-filter coarse top-k, wave-per-key-group ----------------
// grid (256, 4), block 256 (4 waves). Block = 64 queries x 4096 keys (64 tiles).
__global__ __launch_bounds__(256, 5) void topk_thresh(
    const bf16_t* __restrict__ qh, const bf16_t* __restrict__ khg,
    int* __restrict__ fcand, int* __restrict__ fcnt) {
  __shared__ __align__(16) bf16_t KH[64][72];     // 9216 B
  __shared__ __align__(16) float  W8[4][64][8];   // 8192 B: per-wave top-8 group maxima
  __shared__ float Tarr[64];
  __shared__ int   cntq[64];
  __shared__ int   Cand[64][CAP];                 // 10240 B

  const int tid = threadIdx.x;
  const int lane = tid & 63, w = tid >> 6;
  const int l15 = lane & 15, quad = lane >> 4;
  const int qbase = blockIdx.x * 64;
  const int split = blockIdx.y;
  const int key0 = split * (Mm / KSPLIT);

  bf16x8 bq[4][2];
#pragma unroll
  for (int g = 0; g < 4; ++g) {
    const bf16_t* qp = qh + (size_t)(qbase + g * 16 + l15) * HD + quad * 8;
    bq[g][0] = *(const bf16x8*)qp;
    bq[g][1] = *(const bf16x8*)(qp + 32);
  }

  float s8[8];
#pragma unroll
  for (int r = 0; r < 8; ++r) s8[r] = -3.0e38f;

  const int skey = tid >> 2, spart = tid & 3;
  // ---- Pass 1: group maxima -> per-lane top-8 ----
  for (int tile = 0; tile < (Mm / KSPLIT) / 64; ++tile) {
    __syncthreads();
    {
      const uint4* src = (const uint4*)(khg + (size_t)(key0 + tile * 64 + skey) * HD + spart * 16);
      *(uint4*)&KH[skey][spart * 16]     = src[0];
      *(uint4*)&KH[skey][spart * 16 + 8] = src[1];
    }
    __syncthreads();
    const bf16x8 a0 = *(const bf16x8*)&KH[w * 16 + l15][quad * 8];
    const bf16x8 a1 = *(const bf16x8*)&KH[w * 16 + l15][32 + quad * 8];
    float keep = -3.0e38f;
#pragma unroll
    for (int g = 0; g < 4; ++g) {
      f32x4 acc = {0.f, 0.f, 0.f, 0.f};
      acc = MFMA16(a0, bq[g][0], acc, 0, 0, 0);
      acc = MFMA16(a1, bq[g][1], acc, 0, 0, 0);
      float v = fmaxf(fmaxf(acc[0], acc[1]), fmaxf(acc[2], acc[3]));
      v = fmaxf(v, __shfl_xor(v, 16));
      v = fmaxf(v, __shfl_xor(v, 32));
      if (g == quad) keep = v;
    }
    if (keep > s8[7]) {
      s8[7] = keep;
#pragma unroll
      for (int p = 7; p > 0; --p)
        if (s8[p] > s8[p - 1]) { float t = s8[p]; s8[p] = s8[p - 1]; s8[p - 1] = t; }
    }
  }
  {
    float* dst = &W8[w][quad * 16 + l15][0];
#pragma unroll
    for (int r = 0; r < 8; ++r) dst[r] = s8[r];
  }
  __syncthreads();
  if (tid < 64) {
    float t8[8];
#pragma unroll
    for (int r = 0; r < 8; ++r) t8[r] = -3.0e38f;
#pragma unroll
    for (int wv2 = 0; wv2 < 4; ++wv2) {
      float4 u0 = *(const float4*)&W8[wv2][tid][0];
      float4 u1 = *(const float4*)&W8[wv2][tid][4];
      float vals[8] = {u0.x, u0.y, u0.z, u0.w, u1.x, u1.y, u1.z, u1.w};
#pragma unroll
      for (int r = 0; r < 8; ++r) {
        float v = vals[r];
        if (v > t8[7]) {
          t8[7] = v;
#pragma unroll
          for (int p = 7; p > 0; --p)
            if (t8[p] > t8[p - 1]) { float tt = t8[p]; t8[p] = t8[p - 1]; t8[p - 1] = tt; }
        }
      }
    }
    Tarr[tid] = t8[7];
    cntq[tid] = 0;
  }
  __syncthreads();
  float Tq[4];
#pragma unroll
  for (int g = 0; g < 4; ++g) Tq[g] = Tarr[g * 16 + l15];

  // ---- Pass 2: bit-identical replay, push survivors ----
  for (int tile = 0; tile < (Mm / KSPLIT) / 64; ++tile) {
    __syncthreads();
    {
      const uint4* src = (const uint4*)(khg + (size_t)(key0 + tile * 64 + skey) * HD + spart * 16);
      *(uint4*)&KH[skey][spart * 16]     = src[0];
      *(uint4*)&KH[skey][spart * 16 + 8] = src[1];
    }
    __syncthreads();
    const bf16x8 a0 = *(const bf16x8*)&KH[w * 16 + l15][quad * 8];
    const bf16x8 a1 = *(const bf16x8*)&KH[w * 16 + l15][32 + quad * 8];
#pragma unroll
    for (int g = 0; g < 4; ++g) {
      f32x4 acc = {0.f, 0.f, 0.f, 0.f};
      acc = MFMA16(a0, bq[g][0], acc, 0, 0, 0);
      acc = MFMA16(a1, bq[g][1], acc, 0, 0, 0);
      const int kb = key0 + tile * 64 + w * 16 + quad * 4;
      const int qq = g * 16 + l15;
#pragma unroll
      for (int r = 0; r < 4; ++r) {
        if (acc[r] >= Tq[g]) {
          int pos = atomicAdd(&cntq[qq], 1);
          if (pos < CAP) Cand[qq][pos] = kb + r;
        }
      }
    }
  }
  __syncthreads();
  if (tid < 64) {
    int c = cntq[tid];
    fcnt[(size_t)split * NQ + qbase + tid] = (c < CAP) ? c : CAP;
  }
  for (int i = tid; i < 64 * CAP; i += 256) {
    int q = i / CAP, s = i - q * CAP;
    fcand[((size_t)split * NQ + qbase + q) * CAP + s] = Cand[q][s];
  }
}

// ---------------- Kernel 3: exact f32 rescore of candidates -> top-8 ----------------
// grid NQ/64 blocks x 64 threads: one query per lane, all 256 CUs covered.
__global__ __launch_bounds__(64) void rescore8(
    const float* __restrict__ qf, const float* __restrict__ mk,
    const int* __restrict__ fcand, const int* __restrict__ fcnt,
    int* __restrict__ f8) {
  const int qid = blockIdx.x * 64 + threadIdx.x;
  float q[64];
#pragma unroll
  for (int c = 0; c < 16; ++c) {
    float4 v4 = *(const float4*)(qf + (size_t)qid * HD + 4 * c);
    q[4*c]=v4.x; q[4*c+1]=v4.y; q[4*c+2]=v4.z; q[4*c+3]=v4.w;
  }
  float sc[TK]; int id[TK];
#pragma unroll
  for (int r = 0; r < TK; ++r) { sc[r] = -3.0e38f; id[r] = 0x7fffffff; }
#pragma unroll 1
  for (int sp = 0; sp < KSPLIT; ++sp) {
    int cnt = fcnt[(size_t)sp * NQ + qid];
    if (cnt > CAP) cnt = CAP;
#pragma unroll 1
    for (int c = 0; c < cnt; ++c) {
      int kidx = fcand[((size_t)sp * NQ + qid) * CAP + c] & (Mm - 1);
      const float4* kr = (const float4*)(mk + (size_t)kidx * HD);
      float a0 = 0, a1 = 0, a2 = 0, a3 = 0;
#pragma unroll
      for (int cc = 0; cc < 16; ++cc) {
        float4 kv = kr[cc];
        a0 += q[4*cc]*kv.x; a1 += q[4*cc+1]*kv.y; a2 += q[4*cc+2]*kv.z; a3 += q[4*cc+3]*kv.w;
      }
      float s = (a0 + a1) + (a2 + a3);
      if (s > sc[TK - 1] || (s == sc[TK - 1] && kidx < id[TK - 1])) {
        sc[TK - 1] = s; id[TK - 1] = kidx;
#pragma unroll
        for (int p = TK - 1; p > 0; --p) {
          bool sw = (sc[p] > sc[p - 1]) || (sc[p] == sc[p - 1] && id[p] < id[p - 1]);
          if (sw) {
            float ts = sc[p]; sc[p] = sc[p - 1]; sc[p - 1] = ts;
            int   ti = id[p]; id[p] = id[p - 1]; id[p - 1] = ti;
          }
        }
      }
    }
  }
#pragma unroll
  for (int r = 0; r < TK; ++r) f8[(size_t)qid * TK + r] = id[r] & (Mm - 1);
}

// ---------------- Kernel 4: unified MFMA flash attention (mem gather + local causal) ----------------
// grid (8 qt, 32 bh, 3 chunk), block 256 (4 waves). Block = 64 queries of one bh.
// mem tiles split 24/24/16 across chunks; chunk 2 also does the local causal tiles.
// V staged PRE-SPLIT as transposed bf16 VTH/VTL (paired-key packed b32 writes, conflict-free),
// removing the per-thread per-tile f32->bf16 re-split from the PV loop.
// T14: tile t+1's global loads (f8 idx + K/V rows) issue at start of compute(t) into regs,
// so the barrier-bounded staging phase is pure reg->LDS.
__global__ __launch_bounds__(256) void flash_mfma(
    const bf16_t* __restrict__ qh, const bf16_t* __restrict__ ql,
    const float* __restrict__ kf, const float* __restrict__ vf,
    const float* __restrict__ mk, const float* __restrict__ mv,
    const int* __restrict__ f8, float* __restrict__ ml, float* __restrict__ pacc) {
  __shared__ __align__(16) bf16_t KH[64][72];    // 9216 B
  __shared__ __align__(16) bf16_t KL[64][72];    // 9216 B
  __shared__ __align__(16) bf16_t VTH[64][68];   // 8704 B: V^T hi bf16, stride 68
  __shared__ __align__(16) bf16_t VTL[64][68];   // 8704 B
  __shared__ __align__(16) bf16_t PH[64][72];    // 9216 B
  __shared__ __align__(16) bf16_t PL[64][72];    // 9216 B  (total 54272 -> 3 blocks/CU)

  const int tid = threadIdx.x;
  const int lane = tid & 63, w = tid >> 6;
  const int l15 = lane & 15, quad = lane >> 4;
  const int qt = blockIdx.x, bh = blockIdx.y, chunk = blockIdx.z;
  const int il = qt * 64 + w * 16 + l15;
  const int qid = bh * Ls + il;
  const bf16x8 qh0 = *(const bf16x8*)(qh + (size_t)qid * HD + quad * 8);
  const bf16x8 qh1 = *(const bf16x8*)(qh + (size_t)qid * HD + 32 + quad * 8);
  const bf16x8 ql0 = *(const bf16x8*)(ql + (size_t)qid * HD + quad * 8);
  const bf16x8 ql1 = *(const bf16x8*)(ql + (size_t)qid * HD + 32 + quad * 8);

  f32x4 O[4] = {};
  float m = -3.0e38f, lsum = 0.f;
  const float scale = 0.125f;
  const int tbase = chunk * 24;                       // mem tile base: 0 / 24 / 48
  const int nmem  = (chunk == 2) ? 16 : 24;           // mem tiles this chunk
  const int ntiles = (chunk == 2) ? 17 + qt : 24;     // + local causal tiles on chunk 2
  const int skey = tid >> 2, spart = tid & 3;         // K staging: 1 key x 16 dims
  const int kpair = tid & 31, dgroup = tid >> 5;      // V staging: 2 keys x 8 dims

  float kreg[16], va[8], vb[8];
  auto stage_load = [&](int t) {
    const float *ks, *vsa, *vsb;
    if (chunk == 2 && t >= nmem) {
      int jlK = (t - nmem) * 64 + skey;
      ks = kf + ((size_t)bh * Ls + jlK) * HD + spart * 16;
      int jlV = (t - nmem) * 64 + 2 * kpair;
      vsa = vf + ((size_t)bh * Ls + jlV) * HD + dgroup * 8;
      vsb = vsa + HD;
    } else {
      int jgK = (tbase + t) * 64 + skey;
      int sK = f8[((size_t)bh * Ls + (jgK >> 3)) * TK + (jgK & 7)] & (Mm - 1);
      ks = mk + (size_t)sK * HD + spart * 16;
      int jgV = (tbase + t) * 64 + 2 * kpair;          // even -> pair stays in one f8 row
      int2 s2 = *(const int2*)(f8 + ((size_t)bh * Ls + (jgV >> 3)) * TK + (jgV & 7));
      vsa = mv + (size_t)(s2.x & (Mm - 1)) * HD + dgroup * 8;
      vsb = mv + (size_t)(s2.y & (Mm - 1)) * HD + dgroup * 8;
    }
    ld8f(ks, kreg); ld8f(ks + 8, kreg + 8);
    ld8f(vsa, va);
    ld8f(vsb, vb);
  };
  stage_load(0);

  for (int tile = 0; tile < ntiles; ++tile) {
    const bool local_tile = (chunk == 2) && (tile >= nmem);
    __syncthreads();
    {
      // K: split in reg -> KH/KL rows (same layout as before)
      bf16x8 h0, l0, h1, l1;
      split8(kreg, h0, l0); split8(kreg + 8, h1, l1);
      *(bf16x8*)&KH[skey][spart * 16]     = h0;
      *(bf16x8*)&KH[skey][spart * 16 + 8] = h1;
      *(bf16x8*)&KL[skey][spart * 16]     = l0;
      *(bf16x8*)&KL[skey][spart * 16 + 8] = l1;
      // V: split 2 keys x 8 dims in reg, pack pairs -> b32 transposed writes
#pragma unroll
      for (int j = 0; j < 8; ++j) {
        bf16_t ha = (bf16_t)va[j]; bf16_t la = (bf16_t)(va[j] - (float)ha);
        bf16_t hb = (bf16_t)vb[j]; bf16_t lb = (bf16_t)(vb[j] - (float)hb);
        const int d = dgroup * 8 + j;
        bf16x2 th; th[0] = ha; th[1] = hb;
        bf16x2 tl; tl[0] = la; tl[1] = lb;
        *(bf16x2*)&VTH[d][2 * kpair] = th;
        *(bf16x2*)&VTL[d][2 * kpair] = tl;
      }
    }
    __syncthreads();
    if (tile + 1 < ntiles) stage_load(tile + 1);   // overlap next-tile HBM with compute

    f32x4 S[4];
    __builtin_amdgcn_s_setprio(1);
#pragma unroll
    for (int sub = 0; sub < 4; ++sub) {
      const bf16x8 ah0 = *(const bf16x8*)&KH[sub * 16 + l15][quad * 8];
      const bf16x8 ah1 = *(const bf16x8*)&KH[sub * 16 + l15][32 + quad * 8];
      const bf16x8 al0 = *(const bf16x8*)&KL[sub * 16 + l15][quad * 8];
      const bf16x8 al1 = *(const bf16x8*)&KL[sub * 16 + l15][32 + quad * 8];
      f32x4 acc = {0.f, 0.f, 0.f, 0.f};
      acc = MFMA16(ah0, qh0, acc, 0, 0, 0);
      acc = MFMA16(ah1, qh1, acc, 0, 0, 0);
      acc = MFMA16(al0, qh0, acc, 0, 0, 0);
      acc = MFMA16(al1, qh1, acc, 0, 0, 0);
      acc = MFMA16(ah0, ql0, acc, 0, 0, 0);
      acc = MFMA16(ah1, ql1, acc, 0, 0, 0);
#pragma unroll
      for (int r = 0; r < 4; ++r) {
        float sv = acc[r] * scale;
        if (local_tile && ((tile - nmem) * 64 + sub * 16 + quad * 4 + r) > il) sv = -3.0e38f;
        S[sub][r] = sv;
      }
    }
    __builtin_amdgcn_s_setprio(0);
    float tm = -3.0e38f;
#pragma unroll
    for (int sub = 0; sub < 4; ++sub)
#pragma unroll
      for (int r = 0; r < 4; ++r) tm = fmaxf(tm, S[sub][r]);
    tm = fmaxf(tm, __shfl_xor(tm, 16));
    tm = fmaxf(tm, __shfl_xor(tm, 32));
    float mnew = fmaxf(m, tm);
    float alpha = __expf(m - mnew);
    lsum *= alpha;
#pragma unroll
    for (int t = 0; t < 4; ++t) O[t] *= alpha;
    m = mnew;
#pragma unroll
    for (int sub = 0; sub < 4; ++sub) {
      bf16_t ph4[4], pl4[4];
#pragma unroll
      for (int r = 0; r < 4; ++r) {
        float p = __expf(S[sub][r] - mnew);
        lsum += p;
        bf16_t hv = (bf16_t)p;
        ph4[r] = hv;
        pl4[r] = (bf16_t)(p - (float)hv);
      }
      *(uint2*)&PH[w * 16 + l15][sub * 16 + quad * 4] = *(uint2*)ph4;
      *(uint2*)&PL[w * 16 + l15][sub * 16 + quad * 4] = *(uint2*)pl4;
    }
    const bf16x8 ph0 = *(const bf16x8*)&PH[w * 16 + l15][quad * 8];
    const bf16x8 ph1 = *(const bf16x8*)&PH[w * 16 + l15][32 + quad * 8];
    const bf16x8 pl0 = *(const bf16x8*)&PL[w * 16 + l15][quad * 8];
    const bf16x8 pl1 = *(const bf16x8*)&PL[w * 16 + l15][32 + quad * 8];
    __builtin_amdgcn_s_setprio(1);
#pragma unroll
    for (int t = 0; t < 4; ++t) {
      const bf16x8 vh0 = ld8h(&VTH[t * 16 + l15][quad * 8]);
      const bf16x8 vh1 = ld8h(&VTH[t * 16 + l15][32 + quad * 8]);
      const bf16x8 vl0 = ld8h(&VTL[t * 16 + l15][quad * 8]);
      const bf16x8 vl1 = ld8h(&VTL[t * 16 + l15][32 + quad * 8]);
      O[t] = MFMA16(vh0, ph0, O[t], 0, 0, 0);
      O[t] = MFMA16(vh1, ph1, O[t], 0, 0, 0);
      O[t] = MFMA16(vl0, ph0, O[t], 0, 0, 0);
      O[t] = MFMA16(vl1, ph1, O[t], 0, 0, 0);
      O[t] = MFMA16(vh0, pl0, O[t], 0, 0, 0);
      O[t] = MFMA16(vh1, pl1, O[t], 0, 0, 0);
    }
    __builtin_amdgcn_s_setprio(0);
  }
  lsum += __shfl_xor(lsum, 16);
  lsum += __shfl_xor(lsum, 32);
  if (quad == 0) {
    ml[((size_t)chunk * NQ + qid) * 2 + 0] = m;
    ml[((size_t)chunk * NQ + qid) * 2 + 1] = lsum;
  }
  float* pa = pacc + ((size_t)chunk * NQ + qid) * 64;
#pragma unroll
  for (int t = 0; t < 4; ++t) {
    float4 v4; v4.x = O[t][0]; v4.y = O[t][1]; v4.z = O[t][2]; v4.w = O[t][3];
    *(float4*)(pa + t * 16 + quad * 4) = v4;
  }
}

// ---------------- Kernel 5: O-projection with fused 3-way LSE combine, 3-term split MFMA ----------------
__global__ __launch_bounds__(256) void oproj_comb(
    const float* __restrict__ ml, const float* __restrict__ pacc,
    const float* __restrict__ Wo, const float* __restrict__ bo,
    float* __restrict__ out) {
  const int tid = threadIdx.x;
  const int lane = tid & 63, wv = tid >> 6;
  const int l15 = lane & 15, quad = lane >> 4;
  const int mrow = blockIdx.x * 64 + wv * 16 + l15;    // token row 0..1023
  const int b = mrow >> 9, l = mrow & 511;
  const int ncol0 = blockIdx.y * 64;
  f32x4 acc[4] = {};
  for (int kk = 0; kk < Dd; kk += 32) {
    const int h = kk >> 6;
    const size_t qid = (size_t)(b * Hh + h) * Ls + l;
    float m0 = ml[qid * 2 + 0],                    l0 = ml[qid * 2 + 1];
    float m1 = ml[((size_t)NQ + qid) * 2 + 0],     l1 = ml[((size_t)NQ + qid) * 2 + 1];
    float m2 = ml[((size_t)2 * NQ + qid) * 2 + 0], l2 = ml[((size_t)2 * NQ + qid) * 2 + 1];
    float M = fmaxf(m0, fmaxf(m1, m2));
    float w0 = __expf(m0 - M), w1 = __expf(m1 - M), w2 = __expf(m2 - M);
    float inv = 1.f / (w0 * l0 + w1 * l1 + w2 * l2);
    const int d0 = (kk & 63) + quad * 8;
    float a0v[8], a1v[8], a2v[8], av[8];
    ld8f(pacc + qid * 64 + d0, a0v);
    ld8f(pacc + ((size_t)NQ + qid) * 64 + d0, a1v);
    ld8f(pacc + ((size_t)2 * NQ + qid) * 64 + d0, a2v);
#pragma unroll
    for (int j = 0; j < 8; ++j) av[j] = (w0 * a0v[j] + w1 * a1v[j] + w2 * a2v[j]) * inv;
    bf16x8 ahi, alo; split8(av, ahi, alo);
#pragma unroll
    for (int t = 0; t < 4; ++t) {
      float wv8[8]; ld8f(Wo + (size_t)(ncol0 + t * 16 + l15) * Dd + kk + quad * 8, wv8);
      bf16x8 whi, wlo; split8(wv8, whi, wlo);
      acc[t] = MFMA16(ahi, whi, acc[t], 0, 0, 0);
      acc[t] = MFMA16(alo, whi, acc[t], 0, 0, 0);
      acc[t] = MFMA16(ahi, wlo, acc[t], 0, 0, 0);
    }
  }
#pragma unroll
  for (int t = 0; t < 4; ++t) {
    int col = ncol0 + t * 16 + l15;
    float bb = bo[col];
#pragma unroll
    for (int r = 0; r < 4; ++r) {
      int row = blockIdx.x * 64 + wv * 16 + quad * 4 + r;
      out[(size_t)row * Dd + col] = acc[t][r] + bb;
    }
  }
}

extern "C" void kernel_launch(void* const* d_in, const int* in_sizes, int n_in,
                              void* d_out, int out_size, void* d_ws, size_t ws_size,
                              hipStream_t stream) {
  (void)in_sizes; (void)n_in;
  const float* x  = (const float*)d_in[0];
  const float* mk = (const float*)d_in[1];
  const float* mv = (const float*)d_in[2];
  const float* Wq = (const float*)d_in[3];
  const float* bq = (const float*)d_in[4];
  const float* Wk = (const float*)d_in[5];
  const float* bk = (const float*)d_in[6];
  const float* Wv = (const float*)d_in[7];
  const float* bv = (const float*)d_in[8];
  const float* Wo = (const float*)d_in[9];
  const float* bo = (const float*)d_in[10];
  float* ws = (float*)d_ws;

  if (ws_size < WS_BYTES) {   // constant per-problem -> graph-safe
    float v = (float)(ws_size >> 20) + 0.5f;
    ws_sentinel<<<(out_size + 255) / 256, 256, 0, stream>>>((float*)d_out, out_size, v);
    return;
  }

  float*  QF    = ws + OFF_QF;
  float*  KF    = ws + OFF_KF;
  float*  VF    = ws + OFF_VF;
  bf16_t* QH    = (bf16_t*)(ws + OFF_QH);
  bf16_t* QL    = (bf16_t*)(ws + OFF_QL);
  bf16_t* KHG   = (bf16_t*)(ws + OFF_KHG);
  int*    FCAND = (int*)(ws + OFF_FCAND);
  int*    FCNT  = (int*)(ws + OFF_FCNT);
  int*    F8    = (int*)(ws + OFF_F8);
  float*  ML    = ws + OFF_ML;
  float*  PA    = ws + OFF_PA;

  prep_keys<<<(Mm * HD) / (256 * 8), 256, 0, stream>>>(mk, KHG);
  qkv_mfma<<<dim3(16, 16, 3), 256, 0, stream>>>(x, Wq, bq, Wk, bk, Wv, bv, QF, QH, QL, KF, VF);
  topk_thresh<<<dim3(NQ / 64, KSPLIT), 256, 0, stream>>>(QH, KHG, FCAND, FCNT);
  rescore8<<<NQ / 64, 64, 0, stream>>>(QF, mk, FCAND, FCNT, F8);
  flash_mfma<<<dim3(8, 32, 3), 256, 0, stream>>>(QH, QL, KF, VF, mk, mv, F8, ML, PA);
  oproj_comb<<<dim3(16, 16), 256, 0, stream>>>(ML, PA, Wo, bo, (float*)d_out);
}

// Round 2
// 596.361 us; speedup vs baseline: 1.0189x; 1.0044x over previous
//
#include <hip/hip_runtime.h>

typedef __bf16 bf16_t;
typedef __bf16 bf16x8 __attribute__((ext_vector_type(8)));
typedef __bf16 bf16x4 __attribute__((ext_vector_type(4)));
typedef __bf16 bf16x2 __attribute__((ext_vector_type(2)));
typedef float f32x4 __attribute__((ext_vector_type(4)));

#define DEV __device__ __forceinline__
#define MFMA16 __builtin_amdgcn_mfma_f32_16x16x32_bf16

constexpr int Bb = 2, Ls = 512, Dd = 1024, Hh = 16, HD = 64, Mm = 16384, TK = 8;
constexpr int KSPLIT = 4;          // key splits for topk occupancy
constexpr int CAP = 40;            // candidate buffer per (query, split); E[count]~9
constexpr int NQ = Bb * Ls * Hh;   // 16384 query-heads; bh-major qid = (b*16+h)*512 + l
constexpr int CH = 3;              // attention chunks: mem 24/24/16 tiles + local on chunk 2

// f32-unit workspace layout (~43 MB; >=47.3 MB known available from R4)
constexpr size_t OFF_QF   = 0;                                    // Q f32 [NQ][64]
constexpr size_t OFF_KF   = OFF_QF + (size_t)NQ * HD;             // K f32 [NQ][64]
constexpr size_t OFF_VF   = OFF_KF + (size_t)NQ * HD;             // V f32 [NQ][64]
constexpr size_t OFF_QH   = OFF_VF + (size_t)NQ * HD;             // Q hi bf16 [NQ][64]
constexpr size_t OFF_QL   = OFF_QH + (size_t)NQ * HD / 2;         // Q lo bf16
constexpr size_t OFF_KHG  = OFF_QL + (size_t)NQ * HD / 2;         // mem keys bf16 [M][64]
constexpr size_t OFF_FCAND = OFF_KHG + (size_t)Mm * HD / 2;       // int [KSPLIT][NQ][CAP]
constexpr size_t OFF_FCNT  = OFF_FCAND + (size_t)KSPLIT * NQ * CAP; // int [KSPLIT][NQ]
constexpr size_t OFF_F8   = OFF_FCNT + (size_t)KSPLIT * NQ;       // int [NQ][8]
constexpr size_t OFF_ML   = OFF_F8 + (size_t)NQ * TK;             // (m,l) [CH][NQ][2]
constexpr size_t OFF_PA   = OFF_ML + (size_t)CH * NQ * 2;         // acc [CH][NQ][64]
constexpr size_t WS_ELEMS = OFF_PA + (size_t)CH * NQ * HD + 16;
constexpr size_t WS_BYTES = WS_ELEMS * 4;

DEV void ld8f(const float* p, float* dst) {
  float4 a = *(const float4*)p, b = *(const float4*)(p + 4);
  dst[0]=a.x; dst[1]=a.y; dst[2]=a.z; dst[3]=a.w;
  dst[4]=b.x; dst[5]=b.y; dst[6]=b.z; dst[7]=b.w;
}

DEV void split8(const float* av, bf16x8& hi, bf16x8& lo) {
#pragma unroll
  for (int j = 0; j < 8; ++j) {
    bf16_t h_ = (bf16_t)av[j];
    hi[j] = h_;
    lo[j] = (bf16_t)(av[j] - (float)h_);
  }
}

// 8B-aligned bf16x8 load (rows of stride-68 bf16 arrays are 8B- but not 16B-aligned)
DEV bf16x8 ld8h(const bf16_t* p) {
  bf16x4 a = *(const bf16x4*)p;
  bf16x4 b = *(const bf16x4*)(p + 4);
  bf16x8 r;
#pragma unroll
  for (int i = 0; i < 4; ++i) { r[i] = a[i]; r[i + 4] = b[i]; }
  return r;
}

__global__ __launch_bounds__(256) void ws_sentinel(float* __restrict__ out, int n, float v) {
  int i = blockIdx.x * 256 + threadIdx.x;
  if (i < n) out[i] = v;
}

// ---------------- Kernel 0: pre-convert memory keys to bf16 (once) ----------------
__global__ __launch_bounds__(256) void prep_keys(const float* __restrict__ mk,
                                                 bf16_t* __restrict__ khg) {
  const size_t i = ((size_t)blockIdx.x * 256 + threadIdx.x) * 8;
  float v[8]; ld8f(mk + i, v);
  bf16x8 h;
#pragma unroll
  for (int j = 0; j < 8; ++j) h[j] = (bf16_t)v[j];
  *(bf16x8*)(khg + i) = h;
}

// ---------------- Kernel 1: QKV projection, 3-term split MFMA (~f32-exact) ----------------
__global__ __launch_bounds__(256) void qkv_mfma(
    const float* __restrict__ x,
    const float* __restrict__ Wq, const float* __restrict__ bq,
    const float* __restrict__ Wk, const float* __restrict__ bk,
    const float* __restrict__ Wv, const float* __restrict__ bv,
    float* __restrict__ qf, bf16_t* __restrict__ qh, bf16_t* __restrict__ ql,
    float* __restrict__ kf, float* __restrict__ vf) {
  const int z = blockIdx.z;
  const float* W    = (z == 0) ? Wq : ((z == 1) ? Wk : Wv);
  const float* bias = (z == 0) ? bq : ((z == 1) ? bk : bv);
  const int tid = threadIdx.x;
  const int lane = tid & 63, wv = tid >> 6;
  const int l15 = lane & 15, quad = lane >> 4;
  const int mrow = blockIdx.x * 64 + wv * 16 + l15;
  const int ncol0 = blockIdx.y * 64;
  f32x4 acc[4] = {};
  const size_t abase = (size_t)mrow * Dd + quad * 8;
  for (int kk = 0; kk < Dd; kk += 32) {
    float av[8]; ld8f(x + abase + kk, av);
    bf16x8 ahi, alo; split8(av, ahi, alo);
#pragma unroll
    for (int t = 0; t < 4; ++t) {
      float bv8[8]; ld8f(W + (size_t)(ncol0 + t * 16 + l15) * Dd + kk + quad * 8, bv8);
      bf16x8 bhi, blo; split8(bv8, bhi, blo);
      acc[t] = MFMA16(ahi, bhi, acc[t], 0, 0, 0);
      acc[t] = MFMA16(alo, bhi, acc[t], 0, 0, 0);
      acc[t] = MFMA16(ahi, blo, acc[t], 0, 0, 0);
    }
  }
#pragma unroll
  for (int t = 0; t < 4; ++t) {
    int col = ncol0 + t * 16 + l15;
    int h = col >> 6, hd = col & 63;
    float bb = bias[col];
#pragma unroll
    for (int r = 0; r < 4; ++r) {
      int row = blockIdx.x * 64 + wv * 16 + quad * 4 + r;   // token row = b*512+l
      int b = row >> 9, l = row & 511;
      float val = acc[t][r] + bb;
      size_t o = ((size_t)(b * Hh + h) * Ls + l) * HD + hd;
      if (z == 0) {
        qf[o] = val;
        bf16_t hv = (bf16_t)val;
        qh[o] = hv;
        ql[o] = (bf16_t)(val - (float)hv);
      } else if (z == 1) {
        kf[o] = val;
      } else {
        vf[o] = val;
      }
    }
  }
}

// ---------------- Kernel 2: threshold-filter coarse top-k, barrier-free direct loads ----------------
// grid (256, 4), block 256 (4 waves). Block = 64 queries x 4096 keys (64 tiles).
// Wave w consumes ONLY key rows w*16..w*16+15 per tile -> no cross-wave sharing ->
// LDS staging was pure overhead. Each lane loads its A-fragment straight from L2-resident
// khg (2 MB) with a 1-tile register prefetch; passes are barrier-free.
__global__ __launch_bounds__(256, 5) void topk_thresh(
    const bf16_t* __restrict__ qh, const bf16_t* __restrict__ khg,
    int* __restrict__ fcand, int* __restrict__ fcnt) {
  __shared__ __align__(16) float  W8[4][64][8];   // 8192 B: per-wave top-8 group maxima
  __shared__ float Tarr[64];
  __shared__ int   cntq[64];
  __shared__ int   Cand[64][CAP];                 // 10240 B

  const int tid = threadIdx.x;
  const int lane = tid & 63, w = tid >> 6;
  const int l15 = lane & 15, quad = lane >> 4;
  const int qbase = blockIdx.x * 64;
  const int split = blockIdx.y;
  const int key0 = split * (Mm / KSPLIT);
  constexpr int NT = (Mm / KSPLIT) / 64;          // 64 tiles of 64 keys

  bf16x8 bq[4][2];
#pragma unroll
  for (int g = 0; g < 4; ++g) {
    const bf16_t* qp = qh + (size_t)(qbase + g * 16 + l15) * HD + quad * 8;
    bq[g][0] = *(const bf16x8*)qp;
    bq[g][1] = *(const bf16x8*)(qp + 32);
  }

  // per-lane A-fragment source: key row (w*16 + l15) of each tile, dims quad*8 / 32+quad*8
  const bf16_t* kbase = khg + (size_t)(key0 + w * 16 + l15) * HD + quad * 8;

  float s8[8];
#pragma unroll
  for (int r = 0; r < 8; ++r) s8[r] = -3.0e38f;

  // ---- Pass 1: group maxima -> per-lane top-8 (no barriers) ----
  bf16x8 a0 = *(const bf16x8*)(kbase);
  bf16x8 a1 = *(const bf16x8*)(kbase + 32);
  for (int tile = 0; tile < NT; ++tile) {
    const bf16_t* np = kbase + (size_t)((tile + 1 < NT) ? tile + 1 : 0) * (64 * HD);
    bf16x8 n0 = *(const bf16x8*)(np);
    bf16x8 n1 = *(const bf16x8*)(np + 32);
    float keep = -3.0e38f;
#pragma unroll
    for (int g = 0; g < 4; ++g) {
      f32x4 acc = {0.f, 0.f, 0.f, 0.f};
      acc = MFMA16(a0, bq[g][0], acc, 0, 0, 0);
      acc = MFMA16(a1, bq[g][1], acc, 0, 0, 0);
      float v = fmaxf(fmaxf(acc[0], acc[1]), fmaxf(acc[2], acc[3]));
      v = fmaxf(v, __shfl_xor(v, 16));
      v = fmaxf(v, __shfl_xor(v, 32));
      if (g == quad) keep = v;
    }
    if (keep > s8[7]) {
      s8[7] = keep;
#pragma unroll
      for (int p = 7; p > 0; --p)
        if (s8[p] > s8[p - 1]) { float t = s8[p]; s8[p] = s8[p - 1]; s8[p - 1] = t; }
    }
    a0 = n0; a1 = n1;
  }
  {
    float* dst = &W8[w][quad * 16 + l15][0];
#pragma unroll
    for (int r = 0; r < 8; ++r) dst[r] = s8[r];
  }
  __syncthreads();
  if (tid < 64) {
    float t8[8];
#pragma unroll
    for (int r = 0; r < 8; ++r) t8[r] = -3.0e38f;
#pragma unroll
    for (int wv2 = 0; wv2 < 4; ++wv2) {
      float4 u0 = *(const float4*)&W8[wv2][tid][0];
      float4 u1 = *(const float4*)&W8[wv2][tid][4];
      float vals[8] = {u0.x, u0.y, u0.z, u0.w, u1.x, u1.y, u1.z, u1.w};
#pragma unroll
      for (int r = 0; r < 8; ++r) {
        float v = vals[r];
        if (v > t8[7]) {
          t8[7] = v;
#pragma unroll
          for (int p = 7; p > 0; --p)
            if (t8[p] > t8[p - 1]) { float tt = t8[p]; t8[p] = t8[p - 1]; t8[p - 1] = tt; }
        }
      }
    }
    Tarr[tid] = t8[7];
    cntq[tid] = 0;
  }
  __syncthreads();
  float Tq[4];
#pragma unroll
  for (int g = 0; g < 4; ++g) Tq[g] = Tarr[g * 16 + l15];

  // ---- Pass 2: bit-identical replay (same operands -> same scores), push survivors ----
  a0 = *(const bf16x8*)(kbase);
  a1 = *(const bf16x8*)(kbase + 32);
  for (int tile = 0; tile < NT; ++tile) {
    const bf16_t* np = kbase + (size_t)((tile + 1 < NT) ? tile + 1 : 0) * (64 * HD);
    bf16x8 n0 = *(const bf16x8*)(np);
    bf16x8 n1 = *(const bf16x8*)(np + 32);
#pragma unroll
    for (int g = 0; g < 4; ++g) {
      f32x4 acc = {0.f, 0.f, 0.f, 0.f};
      acc = MFMA16(a0, bq[g][0], acc, 0, 0, 0);
      acc = MFMA16(a1, bq[g][1], acc, 0, 0, 0);
      const int kb = key0 + tile * 64 + w * 16 + quad * 4;
      const int qq = g * 16 + l15;
#pragma unroll
      for (int r = 0; r < 4; ++r) {
        if (acc[r] >= Tq[g]) {
          int pos = atomicAdd(&cntq[qq], 1);
          if (pos < CAP) Cand[qq][pos] = kb + r;
        }
      }
    }
    a0 = n0; a1 = n1;
  }
  __syncthreads();
  if (tid < 64) {
    int c = cntq[tid];
    fcnt[(size_t)split * NQ + qbase + tid] = (c < CAP) ? c : CAP;
  }
  for (int i = tid; i < 64 * CAP; i += 256) {
    int q = i / CAP, s = i - q * CAP;
    fcand[((size_t)split * NQ + qbase + q) * CAP + s] = Cand[q][s];
  }
}

// ---------------- Kernel 3: exact f32 rescore of candidates -> top-8 ----------------
// grid NQ/64 blocks x 64 threads: one query per lane, all 256 CUs covered.
__global__ __launch_bounds__(64) void rescore8(
    const float* __restrict__ qf, const float* __restrict__ mk,
    const int* __restrict__ fcand, const int* __restrict__ fcnt,
    int* __restrict__ f8) {
  const int qid = blockIdx.x * 64 + threadIdx.x;
  float q[64];
#pragma unroll
  for (int c = 0; c < 16; ++c) {
    float4 v4 = *(const float4*)(qf + (size_t)qid * HD + 4 * c);
    q[4*c]=v4.x; q[4*c+1]=v4.y; q[4*c+2]=v4.z; q[4*c+3]=v4.w;
  }
  float sc[TK]; int id[TK];
#pragma unroll
  for (int r = 0; r < TK; ++r) { sc[r] = -3.0e38f; id[r] = 0x7fffffff; }
#pragma unroll 1
  for (int sp = 0; sp < KSPLIT; ++sp) {
    int cnt = fcnt[(size_t)sp * NQ + qid];
    if (cnt > CAP) cnt = CAP;
#pragma unroll 1
    for (int c = 0; c < cnt; ++c) {
      int kidx = fcand[((size_t)sp * NQ + qid) * CAP + c] & (Mm - 1);
      const float4* kr = (const float4*)(mk + (size_t)kidx * HD);
      float a0 = 0, a1 = 0, a2 = 0, a3 = 0;
#pragma unroll
      for (int cc = 0; cc < 16; ++cc) {
        float4 kv = kr[cc];
        a0 += q[4*cc]*kv.x; a1 += q[4*cc+1]*kv.y; a2 += q[4*cc+2]*kv.z; a3 += q[4*cc+3]*kv.w;
      }
      float s = (a0 + a1) + (a2 + a3);
      if (s > sc[TK - 1] || (s == sc[TK - 1] && kidx < id[TK - 1])) {
        sc[TK - 1] = s; id[TK - 1] = kidx;
#pragma unroll
        for (int p = TK - 1; p > 0; --p) {
          bool sw = (sc[p] > sc[p - 1]) || (sc[p] == sc[p - 1] && id[p] < id[p - 1]);
          if (sw) {
            float ts = sc[p]; sc[p] = sc[p - 1]; sc[p - 1] = ts;
            int   ti = id[p]; id[p] = id[p - 1]; id[p - 1] = ti;
          }
        }
      }
    }
  }
#pragma unroll
  for (int r = 0; r < TK; ++r) f8[(size_t)qid * TK + r] = id[r] & (Mm - 1);
}

// ---------------- Kernel 4: unified MFMA flash attention (mem gather + local causal) ----------------
// grid (8 qt, 32 bh, 3 chunk), block 256 (4 waves). Block = 64 queries of one bh.
// mem tiles split 24/24/16 across chunks; chunk 2 also does the local causal tiles.
// V staged PRE-SPLIT as transposed bf16 VTH/VTL (paired-key packed b32 writes, conflict-free).
// T14: tile t+1's global loads (f8 idx + K/V rows) issue at start of compute(t) into regs.
__global__ __launch_bounds__(256) void flash_mfma(
    const bf16_t* __restrict__ qh, const bf16_t* __restrict__ ql,
    const float* __restrict__ kf, const float* __restrict__ vf,
    const float* __restrict__ mk, const float* __restrict__ mv,
    const int* __restrict__ f8, float* __restrict__ ml, float* __restrict__ pacc) {
  __shared__ __align__(16) bf16_t KH[64][72];    // 9216 B
  __shared__ __align__(16) bf16_t KL[64][72];    // 9216 B
  __shared__ __align__(16) bf16_t VTH[64][68];   // 8704 B: V^T hi bf16, stride 68
  __shared__ __align__(16) bf16_t VTL[64][68];   // 8704 B
  __shared__ __align__(16) bf16_t PH[64][72];    // 9216 B
  __shared__ __align__(16) bf16_t PL[64][72];    // 9216 B  (total 54272 -> 3 blocks/CU)

  const int tid = threadIdx.x;
  const int lane = tid & 63, w = tid >> 6;
  const int l15 = lane & 15, quad = lane >> 4;
  const int qt = blockIdx.x, bh = blockIdx.y, chunk = blockIdx.z;
  const int il = qt * 64 + w * 16 + l15;
  const int qid = bh * Ls + il;
  const bf16x8 qh0 = *(const bf16x8*)(qh + (size_t)qid * HD + quad * 8);
  const bf16x8 qh1 = *(const bf16x8*)(qh + (size_t)qid * HD + 32 + quad * 8);
  const bf16x8 ql0 = *(const bf16x8*)(ql + (size_t)qid * HD + quad * 8);
  const bf16x8 ql1 = *(const bf16x8*)(ql + (size_t)qid * HD + 32 + quad * 8);

  f32x4 O[4] = {};
  float m = -3.0e38f, lsum = 0.f;
  const float scale = 0.125f;
  const int tbase = chunk * 24;                       // mem tile base: 0 / 24 / 48
  const int nmem  = (chunk == 2) ? 16 : 24;           // mem tiles this chunk
  const int ntiles = (chunk == 2) ? 17 + qt : 24;     // + local causal tiles on chunk 2
  const int skey = tid >> 2, spart = tid & 3;         // K staging: 1 key x 16 dims
  const int kpair = tid & 31, dgroup = tid >> 5;      // V staging: 2 keys x 8 dims

  float kreg[16], va[8], vb[8];
  auto stage_load = [&](int t) {
    const float *ks, *vsa, *vsb;
    if (chunk == 2 && t >= nmem) {
      int jlK = (t - nmem) * 64 + skey;
      ks = kf + ((size_t)bh * Ls + jlK) * HD + spart * 16;
      int jlV = (t - nmem) * 64 + 2 * kpair;
      vsa = vf + ((size_t)bh * Ls + jlV) * HD + dgroup * 8;
      vsb = vsa + HD;
    } else {
      int jgK = (tbase + t) * 64 + skey;
      int sK = f8[((size_t)bh * Ls + (jgK >> 3)) * TK + (jgK & 7)] & (Mm - 1);
      ks = mk + (size_t)sK * HD + spart * 16;
      int jgV = (tbase + t) * 64 + 2 * kpair;          // even -> pair stays in one f8 row
      int2 s2 = *(const int2*)(f8 + ((size_t)bh * Ls + (jgV >> 3)) * TK + (jgV & 7));
      vsa = mv + (size_t)(s2.x & (Mm - 1)) * HD + dgroup * 8;
      vsb = mv + (size_t)(s2.y & (Mm - 1)) * HD + dgroup * 8;
    }
    ld8f(ks, kreg); ld8f(ks + 8, kreg + 8);
    ld8f(vsa, va);
    ld8f(vsb, vb);
  };
  stage_load(0);

  for (int tile = 0; tile < ntiles; ++tile) {
    const bool local_tile = (chunk == 2) && (tile >= nmem);
    __syncthreads();
    {
      // K: split in reg -> KH/KL rows (same layout as before)
      bf16x8 h0, l0, h1, l1;
      split8(kreg, h0, l0); split8(kreg + 8, h1, l1);
      *(bf16x8*)&KH[skey][spart * 16]     = h0;
      *(bf16x8*)&KH[skey][spart * 16 + 8] = h1;
      *(bf16x8*)&KL[skey][spart * 16]     = l0;
      *(bf16x8*)&KL[skey][spart * 16 + 8] = l1;
      // V: split 2 keys x 8 dims in reg, pack pairs -> b32 transposed writes
#pragma unroll
      for (int j = 0; j < 8; ++j) {
        bf16_t ha = (bf16_t)va[j]; bf16_t la = (bf16_t)(va[j] - (float)ha);
        bf16_t hb = (bf16_t)vb[j]; bf16_t lb = (bf16_t)(vb[j] - (float)hb);
        const int d = dgroup * 8 + j;
        bf16x2 th; th[0] = ha; th[1] = hb;
        bf16x2 tl; tl[0] = la; tl[1] = lb;
        *(bf16x2*)&VTH[d][2 * kpair] = th;
        *(bf16x2*)&VTL[d][2 * kpair] = tl;
      }
    }
    __syncthreads();
    if (tile + 1 < ntiles) stage_load(tile + 1);   // overlap next-tile HBM with compute

    f32x4 S[4];
    __builtin_amdgcn_s_setprio(1);
#pragma unroll
    for (int sub = 0; sub < 4; ++sub) {
      const bf16x8 ah0 = *(const bf16x8*)&KH[sub * 16 + l15][quad * 8];
      const bf16x8 ah1 = *(const bf16x8*)&KH[sub * 16 + l15][32 + quad * 8];
      const bf16x8 al0 = *(const bf16x8*)&KL[sub * 16 + l15][quad * 8];
      const bf16x8 al1 = *(const bf16x8*)&KL[sub * 16 + l15][32 + quad * 8];
      f32x4 acc = {0.f, 0.f, 0.f, 0.f};
      acc = MFMA16(ah0, qh0, acc, 0, 0, 0);
      acc = MFMA16(ah1, qh1, acc, 0, 0, 0);
      acc = MFMA16(al0, qh0, acc, 0, 0, 0);
      acc = MFMA16(al1, qh1, acc, 0, 0, 0);
      acc = MFMA16(ah0, ql0, acc, 0, 0, 0);
      acc = MFMA16(ah1, ql1, acc, 0, 0, 0);
#pragma unroll
      for (int r = 0; r < 4; ++r) {
        float sv = acc[r] * scale;
        if (local_tile && ((tile - nmem) * 64 + sub * 16 + quad * 4 + r) > il) sv = -3.0e38f;
        S[sub][r] = sv;
      }
    }
    __builtin_amdgcn_s_setprio(0);
    float tm = -3.0e38f;
#pragma unroll
    for (int sub = 0; sub < 4; ++sub)
#pragma unroll
      for (int r = 0; r < 4; ++r) tm = fmaxf(tm, S[sub][r]);
    tm = fmaxf(tm, __shfl_xor(tm, 16));
    tm = fmaxf(tm, __shfl_xor(tm, 32));
    float mnew = fmaxf(m, tm);
    float alpha = __expf(m - mnew);
    lsum *= alpha;
#pragma unroll
    for (int t = 0; t < 4; ++t) O[t] *= alpha;
    m = mnew;
#pragma unroll
    for (int sub = 0; sub < 4; ++sub) {
      bf16_t ph4[4], pl4[4];
#pragma unroll
      for (int r = 0; r < 4; ++r) {
        float p = __expf(S[sub][r] - mnew);
        lsum += p;
        bf16_t hv = (bf16_t)p;
        ph4[r] = hv;
        pl4[r] = (bf16_t)(p - (float)hv);
      }
      *(uint2*)&PH[w * 16 + l15][sub * 16 + quad * 4] = *(uint2*)ph4;
      *(uint2*)&PL[w * 16 + l15][sub * 16 + quad * 4] = *(uint2*)pl4;
    }
    const bf16x8 ph0 = *(const bf16x8*)&PH[w * 16 + l15][quad * 8];
    const bf16x8 ph1 = *(const bf16x8*)&PH[w * 16 + l15][32 + quad * 8];
    const bf16x8 pl0 = *(const bf16x8*)&PL[w * 16 + l15][quad * 8];
    const bf16x8 pl1 = *(const bf16x8*)&PL[w * 16 + l15][32 + quad * 8];
    __builtin_amdgcn_s_setprio(1);
#pragma unroll
    for (int t = 0; t < 4; ++t) {
      const bf16x8 vh0 = ld8h(&VTH[t * 16 + l15][quad * 8]);
      const bf16x8 vh1 = ld8h(&VTH[t * 16 + l15][32 + quad * 8]);
      const bf16x8 vl0 = ld8h(&VTL[t * 16 + l15][quad * 8]);
      const bf16x8 vl1 = ld8h(&VTL[t * 16 + l15][32 + quad * 8]);
      O[t] = MFMA16(vh0, ph0, O[t], 0, 0, 0);
      O[t] = MFMA16(vh1, ph1, O[t], 0, 0, 0);
      O[t] = MFMA16(vl0, ph0, O[t], 0, 0, 0);
      O[t] = MFMA16(vl1, ph1, O[t], 0, 0, 0);
      O[t] = MFMA16(vh0, pl0, O[t], 0, 0, 0);
      O[t] = MFMA16(vh1, pl1, O[t], 0, 0, 0);
    }
    __builtin_amdgcn_s_setprio(0);
  }
  lsum += __shfl_xor(lsum, 16);
  lsum += __shfl_xor(lsum, 32);
  if (quad == 0) {
    ml[((size_t)chunk * NQ + qid) * 2 + 0] = m;
    ml[((size_t)chunk * NQ + qid) * 2 + 1] = lsum;
  }
  float* pa = pacc + ((size_t)chunk * NQ + qid) * 64;
#pragma unroll
  for (int t = 0; t < 4; ++t) {
    float4 v4; v4.x = O[t][0]; v4.y = O[t][1]; v4.z = O[t][2]; v4.w = O[t][3];
    *(float4*)(pa + t * 16 + quad * 4) = v4;
  }
}

// ---------------- Kernel 5: O-projection with fused 3-way LSE combine, 3-term split MFMA ----------------
__global__ __launch_bounds__(256) void oproj_comb(
    const float* __restrict__ ml, const float* __restrict__ pacc,
    const float* __restrict__ Wo, const float* __restrict__ bo,
    float* __restrict__ out) {
  const int tid = threadIdx.x;
  const int lane = tid & 63, wv = tid >> 6;
  const int l15 = lane & 15, quad = lane >> 4;
  const int mrow = blockIdx.x * 64 + wv * 16 + l15;    // token row 0..1023
  const int b = mrow >> 9, l = mrow & 511;
  const int ncol0 = blockIdx.y * 64;
  f32x4 acc[4] = {};
  for (int kk = 0; kk < Dd; kk += 32) {
    const int h = kk >> 6;
    const size_t qid = (size_t)(b * Hh + h) * Ls + l;
    float m0 = ml[qid * 2 + 0],                    l0 = ml[qid * 2 + 1];
    float m1 = ml[((size_t)NQ + qid) * 2 + 0],     l1 = ml[((size_t)NQ + qid) * 2 + 1];
    float m2 = ml[((size_t)2 * NQ + qid) * 2 + 0], l2 = ml[((size_t)2 * NQ + qid) * 2 + 1];
    float M = fmaxf(m0, fmaxf(m1, m2));
    float w0 = __expf(m0 - M), w1 = __expf(m1 - M), w2 = __expf(m2 - M);
    float inv = 1.f / (w0 * l0 + w1 * l1 + w2 * l2);
    const int d0 = (kk & 63) + quad * 8;
    float a0v[8], a1v[8], a2v[8], av[8];
    ld8f(pacc + qid * 64 + d0, a0v);
    ld8f(pacc + ((size_t)NQ + qid) * 64 + d0, a1v);
    ld8f(pacc + ((size_t)2 * NQ + qid) * 64 + d0, a2v);
#pragma unroll
    for (int j = 0; j < 8; ++j) av[j] = (w0 * a0v[j] + w1 * a1v[j] + w2 * a2v[j]) * inv;
    bf16x8 ahi, alo; split8(av, ahi, alo);
#pragma unroll
    for (int t = 0; t < 4; ++t) {
      float wv8[8]; ld8f(Wo + (size_t)(ncol0 + t * 16 + l15) * Dd + kk + quad * 8, wv8);
      bf16x8 whi, wlo; split8(wv8, whi, wlo);
      acc[t] = MFMA16(ahi, whi, acc[t], 0, 0, 0);
      acc[t] = MFMA16(alo, whi, acc[t], 0, 0, 0);
      acc[t] = MFMA16(ahi, wlo, acc[t], 0, 0, 0);
    }
  }
#pragma unroll
  for (int t = 0; t < 4; ++t) {
    int col = ncol0 + t * 16 + l15;
    float bb = bo[col];
#pragma unroll
    for (int r = 0; r < 4; ++r) {
      int row = blockIdx.x * 64 + wv * 16 + quad * 4 + r;
      out[(size_t)row * Dd + col] = acc[t][r] + bb;
    }
  }
}

extern "C" void kernel_launch(void* const* d_in, const int* in_sizes, int n_in,
                              void* d_out, int out_size, void* d_ws, size_t ws_size,
                              hipStream_t stream) {
  (void)in_sizes; (void)n_in;
  const float* x  = (const float*)d_in[0];
  const float* mk = (const float*)d_in[1];
  const float* mv = (const float*)d_in[2];
  const float* Wq = (const float*)d_in[3];
  const float* bq = (const float*)d_in[4];
  const float* Wk = (const float*)d_in[5];
  const float* bk = (const float*)d_in[6];
  const float* Wv = (const float*)d_in[7];
  const float* bv = (const float*)d_in[8];
  const float* Wo = (const float*)d_in[9];
  const float* bo = (const float*)d_in[10];
  float* ws = (float*)d_ws;

  if (ws_size < WS_BYTES) {   // constant per-problem -> graph-safe
    float v = (float)(ws_size >> 20) + 0.5f;
    ws_sentinel<<<(out_size + 255) / 256, 256, 0, stream>>>((float*)d_out, out_size, v);
    return;
  }

  float*  QF    = ws + OFF_QF;
  float*  KF    = ws + OFF_KF;
  float*  VF    = ws + OFF_VF;
  bf16_t* QH    = (bf16_t*)(ws + OFF_QH);
  bf16_t* QL    = (bf16_t*)(ws + OFF_QL);
  bf16_t* KHG   = (bf16_t*)(ws + OFF_KHG);
  int*    FCAND = (int*)(ws + OFF_FCAND);
  int*    FCNT  = (int*)(ws + OFF_FCNT);
  int*    F8    = (int*)(ws + OFF_F8);
  float*  ML    = ws + OFF_ML;
  float*  PA    = ws + OFF_PA;

  prep_keys<<<(Mm * HD) / (256 * 8), 256, 0, stream>>>(mk, KHG);
  qkv_mfma<<<dim3(16, 16, 3), 256, 0, stream>>>(x, Wq, bq, Wk, bk, Wv, bv, QF, QH, QL, KF, VF);
  topk_thresh<<<dim3(NQ / 64, KSPLIT), 256, 0, stream>>>(QH, KHG, FCAND, FCNT);
  rescore8<<<NQ / 64, 64, 0, stream>>>(QF, mk, FCAND, FCNT, F8);
  flash_mfma<<<dim3(8, 32, 3), 256, 0, stream>>>(QH, QL, KF, VF, mk, mv, F8, ML, PA);
  oproj_comb<<<dim3(16, 16), 256, 0, stream>>>(ML, PA, Wo, bo, (float*)d_out);
}